// Round 3
// baseline (558.671 us; speedup 1.0000x reference)
//
#include <hip/hip_runtime.h>
#include <hip/hip_bf16.h>

typedef __bf16 bf16;
typedef __bf16 bf16x4 __attribute__((ext_vector_type(4)));
typedef __bf16 bf16x8 __attribute__((ext_vector_type(8)));
typedef float f32x4 __attribute__((ext_vector_type(4)));

// problem sizes
#define NN 8192
#define DIN 128
#define DTH 256
#define DH 64

// workspace layout (bytes)
#define OFF_BN   0                               // 256 f32 bn sums (1 KB)
#define OFF_PACC 1024                            // 2 (js) * 8192*64 f32
#define OFF_PDEN (OFF_PACC + 2*8192*64*4)        // 2 (js) * 8192 f32
#define OFF_HX   (OFF_PDEN + 2*8192*4)           // 8192*256 bf16 Hx
#define OFF_X2T  (OFF_HX + 8192*256*2)           // 64*8192 bf16 X2 transposed
#define ZERO_BYTES 1024                          // only bn sums need zeroing

#define E_CONST 2.71828182845904523f

// ---------------------------------------------------------------------------
// BN statistics: per-feature sum and sum-of-squares via per-block partials.
__global__ __launch_bounds__(256) void k_bn_stats(const float* __restrict__ H,
                                                  float* __restrict__ bns) {
    __shared__ float s1[256], s2[256];
    int t = threadIdx.x;
    int f = t & 127, rh = t >> 7;
    int r0 = blockIdx.x * 32 + rh * 16;
    float a = 0.f, b = 0.f;
#pragma unroll
    for (int rr = 0; rr < 16; ++rr) {
        float x = H[(size_t)(r0 + rr) * DIN + f];
        a += x; b += x * x;
    }
    s1[t] = a; s2[t] = b;
    __syncthreads();
    if (t < 128) {
        atomicAdd(&bns[f], s1[t] + s1[t + 128]);
        atomicAdd(&bns[128 + f], s2[t] + s2[t + 128]);
    }
}

// ---------------------------------------------------------------------------
// BN apply + projections: Hx = Hn@Wt+bt (bf16), out1 = leaky(Hn@W1+b1) (fp32,
// written directly to left half of output), X2T[c][row] = Hn@W2+b2 (bf16).
__global__ __launch_bounds__(256) void k_project(
    const float* __restrict__ H, const float* __restrict__ bns,
    const float* __restrict__ gamma, const float* __restrict__ beta,
    const float* __restrict__ Wt, const float* __restrict__ bt,
    const float* __restrict__ W1, const float* __restrict__ b1,
    const float* __restrict__ W2, const float* __restrict__ b2,
    bf16* __restrict__ Hx, bf16* __restrict__ X2T, float* __restrict__ out)
{
    __shared__ float Hn[16 * 128];
    int t = threadIdx.x;
    int r0 = blockIdx.x * 16;
    {   // BN apply: each thread owns feature f = t&127, rows t>>7 + 2p
        int f = t & 127;
        float mean = bns[f] * (1.f / 8192.f);
        float var  = bns[128 + f] * (1.f / 8192.f) - mean * mean;
        float sc = rsqrtf(var + 1e-5f) * gamma[f];
        float sh = beta[f];
        int rb = t >> 7;
#pragma unroll
        for (int p = 0; p < 8; ++p) {
            int row = rb + p * 2;
            float x = H[(size_t)(r0 + row) * DIN + f];
            Hn[row * 128 + f] = (x - mean) * sc + sh;
        }
    }
    __syncthreads();
    {   // Hx = Hn @ Wt + bt : thread -> 4 rows x 4 cols
        int c0 = t & 63, rg = t >> 6;
        float acc[4][4];
#pragma unroll
        for (int i = 0; i < 4; ++i)
#pragma unroll
            for (int j = 0; j < 4; ++j) acc[i][j] = 0.f;
        for (int k = 0; k < 128; ++k) {
            float h[4];
#pragma unroll
            for (int rr = 0; rr < 4; ++rr) h[rr] = Hn[(rg * 4 + rr) * 128 + k];
#pragma unroll
            for (int cc = 0; cc < 4; ++cc) {
                float wv = Wt[k * DTH + c0 + 64 * cc];
#pragma unroll
                for (int rr = 0; rr < 4; ++rr) acc[rr][cc] += h[rr] * wv;
            }
        }
#pragma unroll
        for (int rr = 0; rr < 4; ++rr) {
            int row = r0 + rg * 4 + rr;
#pragma unroll
            for (int cc = 0; cc < 4; ++cc) {
                int c = c0 + 64 * cc;
                Hx[(size_t)row * DTH + c] = (bf16)(acc[rr][cc] + bt[c]);
            }
        }
    }
    {   // out1 (fp32 exact) and X2T (bf16)
        int c = t & 63, rg = t >> 6;
        float a1[4] = {0,0,0,0}, a2[4] = {0,0,0,0};
        for (int k = 0; k < 128; ++k) {
            float w1 = W1[k * DH + c], w2 = W2[k * DH + c];
#pragma unroll
            for (int rr = 0; rr < 4; ++rr) {
                float h = Hn[(rg * 4 + rr) * 128 + k];
                a1[rr] += h * w1; a2[rr] += h * w2;
            }
        }
#pragma unroll
        for (int rr = 0; rr < 4; ++rr) {
            int row = r0 + rg * 4 + rr;
            float v1 = a1[rr] + b1[c];
            out[(size_t)row * 128 + c] = v1 > 0.f ? v1 : 0.01f * v1;
            X2T[(size_t)c * NN + row] = (bf16)(a2[rr] + b2[c]);
        }
    }
}

// ---------------------------------------------------------------------------
// Fused v4: BARRIER-FREE main loop.
// Key insight: each wave's QK A-rows (j = ch*64 + w*16 + li) are wave-private,
// so LDS staging of Hx_j shared nothing -> load fragments direct from global
// (L2-resident). No __syncthreads in the loop => register prefetch of the
// A-matrix stream (256 MB HBM, read exactly once, f32x4-coalesced) is never
// drained; ~24 KB/CU in flight >> Little's-law need (~11 KB).
//  - S^T = mfma(Hx_j, Hx_i): lane holds P^T[j=q*4+r][i=li] = PV B-fragment.
//  - gate -> PV register-only; PV pairs two 64-j chunks (K=32).
//  - aj/A/X2T software-pipelined ~1 pair ahead in registers.
//  - XCD-aware block swizzle (grid 512 = 8*64, bijective).
__global__ __launch_bounds__(256, 2) void k_fused(
    const float* __restrict__ A, const bf16* __restrict__ Hx,
    const bf16* __restrict__ X2T, float* __restrict__ pacc,
    float* __restrict__ pden)
{
    __shared__ float Lf[4 * 2048];   // epilogue cross-wave reduction only

    int t = threadIdx.x;
    int w = t >> 6, l = t & 63;
    int q = l >> 4, li = l & 15;
    int bid = blockIdx.x;
    int rid = (bid & 7) * 64 + (bid >> 3);   // XCD swizzle, bijective (512%8==0)
    int ib = rid >> 1, js = rid & 1;
    int i0 = ib * 32;
    int jb = js * 4096;

    union U8 { uint2 u[2]; bf16x8 v; };

    // Hx_i B-fragments, held in registers for the whole kernel
    bf16x8 hbI[2][8];
#pragma unroll
    for (int n = 0; n < 2; ++n)
#pragma unroll
        for (int ks = 0; ks < 8; ++ks)
            hbI[n][ks] = *(const bf16x8*)&Hx[(size_t)(i0 + n * 16 + li) * DTH + ks * 32 + q * 8];

    // per-lane base pointers
    const bf16*  ajp = Hx  + (size_t)(jb + w * 16 + li) * DTH + q * 8;      // + ch*64*DTH + ks*32
    const float* avp = A   + (size_t)(i0 + li) * NN + jb + w * 16 + q * 4;  // + n*16*NN + ch*64
    const bf16*  xp  = X2T + (size_t)li * NN + jb + w * 16 + q * 4;         // + ct*16*NN + ch*64

    bf16x8 ajE[8], ajO[8];
    f32x4  avE[2], avO[2];
    uint2  xe[4], xo[4];
    f32x4  acc[4][2] = {{{0,0,0,0},{0,0,0,0}},{{0,0,0,0},{0,0,0,0}},
                        {{0,0,0,0},{0,0,0,0}},{{0,0,0,0},{0,0,0,0}}};
    float  dp[2] = {0.f, 0.f};

#define LOAD_AJ(DST, CH)                                                       \
    _Pragma("unroll")                                                          \
    for (int ks = 0; ks < 8; ++ks)                                             \
        DST[ks] = *(const bf16x8*)(ajp + (size_t)(CH) * 64 * DTH + ks * 32);

#define LOAD_AV(DST, CH)                                                       \
    _Pragma("unroll")                                                          \
    for (int n = 0; n < 2; ++n)                                                \
        DST[n] = *(const f32x4*)(avp + (size_t)n * 16 * NN + (CH) * 64);

#define QK_GATE(AJ, AV, CH, PD0, PD1)                                          \
    {                                                                          \
        f32x4 s0 = {0,0,0,0}, s1 = {0,0,0,0};                                  \
        _Pragma("unroll")                                                      \
        for (int ks = 0; ks < 8; ++ks) {                                       \
            s0 = __builtin_amdgcn_mfma_f32_16x16x32_bf16(AJ[ks], hbI[0][ks], s0, 0, 0, 0); \
            s1 = __builtin_amdgcn_mfma_f32_16x16x32_bf16(AJ[ks], hbI[1][ks], s1, 0, 0, 0); \
        }                                                                      \
        int jr0 = jb + (CH) * 64 + w * 16;                                     \
        _Pragma("unroll")                                                      \
        for (int n = 0; n < 2; ++n) {                                          \
            f32x4 sv = n ? s1 : s0;                                            \
            f32x4 am = n ? (AV)[1] : (AV)[0];                                  \
            int ig = i0 + n * 16 + li;                                         \
            _Pragma("unroll")                                                  \
            for (int r = 0; r < 4; ++r) {                                      \
                float s = sv[r];                                               \
                float sig = __builtin_amdgcn_rcpf(1.f + __expf(-s));           \
                float wv = (am[r] > 0.f) ? __expf(sig) : 0.f;                  \
                int jc = jr0 + q * 4 + r;                                      \
                if (ig == jc) wv = E_CONST;                                    \
                dp[n] += wv;                                                   \
                if (n == 0) PD0[r] = (bf16)wv; else PD1[r] = (bf16)wv;         \
            }                                                                  \
        }                                                                      \
    }

    // ---- prologue: aj for chunk 0; A for pair 0 (chunks 0,1)
    LOAD_AJ(ajE, 0)
    LOAD_AV(avE, 0)
    LOAD_AV(avO, 1)

    for (int pr = 0; pr < 32; ++pr) {
        // X2T fragments for this pair (L2-resident; consumed at PV below)
#pragma unroll
        for (int ct = 0; ct < 4; ++ct) {
            xe[ct] = *(const uint2*)(xp + (size_t)ct * 16 * NN + pr * 128);
            xo[ct] = *(const uint2*)(xp + (size_t)ct * 16 * NN + pr * 128 + 64);
        }
        // aj for the odd chunk (consumed after QK-even, ~1 QK phase of cover)
        LOAD_AJ(ajO, 2 * pr + 1)

        bf16x4 pe0, pe1, po0, po1;
        QK_GATE(ajE, avE, 2 * pr, pe0, pe1)

        int prn = (pr + 1 < 32) ? pr + 1 : 31;     // clamped prefetch (harmless dup)
        LOAD_AJ(ajE, 2 * prn)                      // next pair's even chunk
        LOAD_AV(avE, 2 * prn)                      // next pair's A (even)

        QK_GATE(ajO, avO, 2 * pr + 1, po0, po1)
        LOAD_AV(avO, 2 * prn + 1)                  // next pair's A (odd)

        // PV: acc[ct][n] += X2T_frag(ct) * P^T_frag(n), K = 32 (chunk pair)
#pragma unroll
        for (int n = 0; n < 2; ++n) {
            bf16x8 pf;
            bf16x4 pe = n ? pe1 : pe0;
            bf16x4 po = n ? po1 : po0;
            pf[0] = pe[0]; pf[1] = pe[1]; pf[2] = pe[2]; pf[3] = pe[3];
            pf[4] = po[0]; pf[5] = po[1]; pf[6] = po[2]; pf[7] = po[3];
#pragma unroll
            for (int ct = 0; ct < 4; ++ct) {
                U8 xf; xf.u[0] = xe[ct]; xf.u[1] = xo[ct];
                acc[ct][n] = __builtin_amdgcn_mfma_f32_16x16x32_bf16(xf.v, pf, acc[ct][n], 0, 0, 0);
            }
        }
    }
#undef LOAD_AJ
#undef LOAD_AV
#undef QK_GATE

    // ---- epilogue: cross-wave reduce PV partials via LDS, plain stores ----
    float* po = pacc + (size_t)js * NN * DH;
#pragma unroll
    for (int ct = 0; ct < 4; ++ct)
#pragma unroll
        for (int n = 0; n < 2; ++n)
#pragma unroll
            for (int r = 0; r < 4; ++r)
                Lf[w * 2048 + (ct * 16 + q * 4 + r) * 32 + n * 16 + li] = acc[ct][n][r];
    __syncthreads();
#pragma unroll
    for (int p = 0; p < 8; ++p) {
        int idx = t + p * 256;
        float v = Lf[idx] + Lf[2048 + idx] + Lf[4096 + idx] + Lf[6144 + idx];
        po[(size_t)(i0 + (idx & 31)) * DH + (idx >> 5)] = v;
    }
    // denominators: reduce over q-groups in-wave, then cross-wave via LDS
    float dq0 = dp[0], dq1 = dp[1];
    dq0 += __shfl_xor(dq0, 16, 64); dq0 += __shfl_xor(dq0, 32, 64);
    dq1 += __shfl_xor(dq1, 16, 64); dq1 += __shfl_xor(dq1, 32, 64);
    __syncthreads();
    if (l < 16) { Lf[w * 32 + li] = dq0; Lf[w * 32 + 16 + li] = dq1; }
    __syncthreads();
    if (t < 32) {
        float v = Lf[t] + Lf[32 + t] + Lf[64 + t] + Lf[96 + t];
        pden[(size_t)js * NN + i0 + t] = v;
    }
}

// ---------------------------------------------------------------------------
__global__ __launch_bounds__(256) void k_finalize(const float* __restrict__ pacc,
                                                  const float* __restrict__ pden,
                                                  float* __restrict__ out)
{
    int e = blockIdx.x * 256 + threadIdx.x;
    int i = e >> 6, c = e & 63;
    float v = (pacc[e] + pacc[NN * DH + e]) / (pden[i] + pden[NN + i]);
    out[(size_t)i * 128 + 64 + c] = v > 0.f ? v : 0.01f * v;
}

// ---------------------------------------------------------------------------
extern "C" void kernel_launch(void* const* d_in, const int* in_sizes, int n_in,
                              void* d_out, int out_size, void* d_ws, size_t ws_size,
                              hipStream_t stream)
{
    const float* H     = (const float*)d_in[0];
    const float* A     = (const float*)d_in[1];
    const float* gamma = (const float*)d_in[2];
    const float* beta  = (const float*)d_in[3];
    const float* Wt    = (const float*)d_in[4];
    const float* bt    = (const float*)d_in[5];
    const float* W1    = (const float*)d_in[6];
    const float* b1    = (const float*)d_in[7];
    const float* W2    = (const float*)d_in[8];
    const float* b2    = (const float*)d_in[9];
    float* out = (float*)d_out;

    char* ws = (char*)d_ws;
    float* bns  = (float*)(ws + OFF_BN);
    float* pacc = (float*)(ws + OFF_PACC);
    float* pden = (float*)(ws + OFF_PDEN);
    bf16*  Hx   = (bf16*)(ws + OFF_HX);
    bf16*  X2T  = (bf16*)(ws + OFF_X2T);

    hipMemsetAsync(ws + OFF_BN, 0, ZERO_BYTES, stream);
    k_bn_stats<<<256, 256, 0, stream>>>(H, bns);
    k_project<<<512, 256, 0, stream>>>(H, bns, gamma, beta, Wt, bt, W1, b1, W2, b2,
                                       Hx, X2T, out);
    k_fused<<<512, 256, 0, stream>>>(A, Hx, X2T, pacc, pden);
    k_finalize<<<2048, 256, 0, stream>>>(pacc, pden, out);
}